// Round 4
// baseline (4465.717 us; speedup 1.0000x reference)
//
#include <hip/hip_runtime.h>

#define N_USERS 50000
#define N_ENTITIES 100000
#define N_RELATIONS 16
#define N_EDGES 3200000
#define NNZ 2500000
#define CH 64

#define RPB 64            // rows per bucket (= destination rows per block)
#define NB_E 1563         // ceil(N_ENTITIES/64)
#define NB_U 782          // ceil(N_USERS/64)
#define CAP_E 2560        // bucket capacity, mean 2047 +11 sigma
#define CAP_U 3840        // mean 3197 +11 sigma
#define P1_BLOCKS 512

__device__ __forceinline__ unsigned short f2bf(float f) {
    unsigned u = __float_as_uint(f);
    u += 0x7FFF + ((u >> 16) & 1);   // round-to-nearest-even
    return (unsigned short)(u >> 16);
}
__device__ __forceinline__ float bf2f(unsigned short h) {
    return __uint_as_float(((unsigned)h) << 16);
}

// ---------------------------------------------------------------------------
// init: out_entity = entity_emb (f32); out_user = user_emb (f32);
//       curA = bf16(entity_emb)
// ---------------------------------------------------------------------------
__global__ void init_kernel(const float4* __restrict__ user_emb,
                            const float4* __restrict__ entity_emb,
                            ushort4* __restrict__ cur_bf,
                            float4* __restrict__ out_entity,
                            float4* __restrict__ out_user) {
    const int ne4 = N_ENTITIES * CH / 4;  // 1.6M
    const int nu4 = N_USERS * CH / 4;     // 0.8M
    int i = blockIdx.x * blockDim.x + threadIdx.x;
    if (i < ne4) {
        float4 v = entity_emb[i];
        out_entity[i] = v;
        ushort4 b;
        b.x = f2bf(v.x); b.y = f2bf(v.y); b.z = f2bf(v.z); b.w = f2bf(v.w);
        cur_bf[i] = b;
    }
    if (i < nu4) out_user[i] = user_emb[i];
}

// ---------------------------------------------------------------------------
// Bucket-binning pass (KG edges): per-block LDS histogram over all buckets,
// one global atomic per (block,bucket) reserves a contiguous run -> each
// destination line is written by a single block (single XCD), ~1x write amp.
// Payload: tail(17b) | rel(4b)<<17 | rowlocal(6b)<<21, mask fp32.
// ---------------------------------------------------------------------------
__global__ void kg_pass1(const int* __restrict__ head, const int* __restrict__ tail,
                         const int* __restrict__ type, const float* __restrict__ mask,
                         int* __restrict__ gcur, int2* __restrict__ bin) {
    __shared__ int hist[NB_E];
    __shared__ int lbase[NB_E];
    for (int i = threadIdx.x; i < NB_E; i += blockDim.x) hist[i] = 0;
    __syncthreads();
    const int chunk = (N_EDGES + P1_BLOCKS - 1) / P1_BLOCKS;
    int base = blockIdx.x * chunk;
    int lim = min(base + chunk, N_EDGES);
    for (int i = base + (int)threadIdx.x; i < lim; i += blockDim.x)
        atomicAdd(&hist[head[i] >> 6], 1);
    __syncthreads();
    for (int i = threadIdx.x; i < NB_E; i += blockDim.x) {
        int c = hist[i];
        lbase[i] = c ? atomicAdd(&gcur[i], c) : 0;
        hist[i] = 0;  // becomes local cursor
    }
    __syncthreads();
    for (int i = base + (int)threadIdx.x; i < lim; i += blockDim.x) {
        int h = head[i];
        int b = h >> 6;
        int loc = lbase[b] + atomicAdd(&hist[b], 1);
        if (loc < CAP_E)
            bin[(size_t)b * CAP_E + loc] =
                make_int2(tail[i] | ((type[i] - 1) << 17) | ((h & 63) << 21),
                          __float_as_int(mask[i]));
    }
}

// user interactions: payload = col(17b) | rowlocal(6b)<<17, val fp32
__global__ void usr_pass1(const int* __restrict__ rows, const int* __restrict__ cols,
                          const float* __restrict__ vals,
                          int* __restrict__ gcur, int2* __restrict__ bin) {
    __shared__ int hist[NB_U];
    __shared__ int lbase[NB_U];
    for (int i = threadIdx.x; i < NB_U; i += blockDim.x) hist[i] = 0;
    __syncthreads();
    const int chunk = (NNZ + P1_BLOCKS - 1) / P1_BLOCKS;
    int base = blockIdx.x * chunk;
    int lim = min(base + chunk, NNZ);
    for (int i = base + (int)threadIdx.x; i < lim; i += blockDim.x)
        atomicAdd(&hist[rows[i] >> 6], 1);
    __syncthreads();
    for (int i = threadIdx.x; i < NB_U; i += blockDim.x) {
        int c = hist[i];
        lbase[i] = c ? atomicAdd(&gcur[i], c) : 0;
        hist[i] = 0;
    }
    __syncthreads();
    for (int i = base + (int)threadIdx.x; i < lim; i += blockDim.x) {
        int r = rows[i];
        int b = r >> 6;
        int loc = lbase[b] + atomicAdd(&hist[b], 1);
        if (loc < CAP_U)
            bin[(size_t)b * CAP_U + loc] =
                make_int2(cols[i] | ((r & 63) << 17), __float_as_int(vals[i]));
    }
}

// ---------------------------------------------------------------------------
// Merged aggregation: one block per bucket (entity buckets then user buckets).
// 64-row fp32 accumulator in LDS (16 KB), ds_add_f32 atomics (2-way bank
// aliasing = free). Wave-per-edge, bf16 gathers (128 B/row). Epilogue: fused
// L2-normalize (butterfly) + residual add + bf16 next-state write.
// ---------------------------------------------------------------------------
__global__ void __launch_bounds__(256)
agg_kernel(const unsigned short* __restrict__ cur,
           const float* __restrict__ weight,
           const int2* __restrict__ binE, const int* __restrict__ cntE,
           const int2* __restrict__ binU, const int* __restrict__ cntU,
           unsigned short* __restrict__ nxt,
           float* __restrict__ res_e, float* __restrict__ res_u) {
    __shared__ float accum[RPB * CH];          // 16 KB
    __shared__ float wlds[N_RELATIONS * CH];   // 4 KB
    const int b = blockIdx.x;
    const int t = threadIdx.x;
    const int wid = t >> 6;
    const int lane = t & 63;
    for (int i = t; i < RPB * CH; i += 256) accum[i] = 0.f;

    if (b < NB_E) {
        for (int i = t; i < N_RELATIONS * CH; i += 256) wlds[i] = weight[i];
        __syncthreads();
        const int cnt = min(cntE[b], CAP_E);
        const int2* bin = binE + (size_t)b * CAP_E;
        int i = wid;
        for (; i + 4 < cnt; i += 8) {
            int2 p0 = bin[i];
            int2 p1 = bin[i + 4];
            float g0 = bf2f(cur[(size_t)(p0.x & 0x1FFFF) * CH + lane]);
            float g1 = bf2f(cur[(size_t)(p1.x & 0x1FFFF) * CH + lane]);
            float v0 = g0 * __int_as_float(p0.y) * wlds[((p0.x >> 17) & 15) * CH + lane];
            float v1 = g1 * __int_as_float(p1.y) * wlds[((p1.x >> 17) & 15) * CH + lane];
            atomicAdd(&accum[((p0.x >> 21) & 63) * CH + lane], v0);
            atomicAdd(&accum[((p1.x >> 21) & 63) * CH + lane], v1);
        }
        if (i < cnt) {
            int2 p = bin[i];
            float g = bf2f(cur[(size_t)(p.x & 0x1FFFF) * CH + lane]);
            float v = g * __int_as_float(p.y) * wlds[((p.x >> 17) & 15) * CH + lane];
            atomicAdd(&accum[((p.x >> 21) & 63) * CH + lane], v);
        }
        __syncthreads();
        for (int r = wid; r < RPB; r += 4) {
            int grow = b * RPB + r;
            if (grow >= N_ENTITIES) break;
            float x = accum[r * CH + lane];
            float ss = x * x;
            #pragma unroll
            for (int o = 32; o; o >>= 1) ss += __shfl_xor(ss, o, 64);
            float y = x / fmaxf(sqrtf(ss), 1e-12f);
            nxt[(size_t)grow * CH + lane] = f2bf(y);
            res_e[(size_t)grow * CH + lane] += y;
        }
    } else {
        __syncthreads();
        const int ub = b - NB_E;
        const int cnt = min(cntU[ub], CAP_U);
        const int2* bin = binU + (size_t)ub * CAP_U;
        int i = wid;
        for (; i + 4 < cnt; i += 8) {
            int2 p0 = bin[i];
            int2 p1 = bin[i + 4];
            float g0 = bf2f(cur[(size_t)(p0.x & 0x1FFFF) * CH + lane]);
            float g1 = bf2f(cur[(size_t)(p1.x & 0x1FFFF) * CH + lane]);
            atomicAdd(&accum[((p0.x >> 17) & 63) * CH + lane], g0 * __int_as_float(p0.y));
            atomicAdd(&accum[((p1.x >> 17) & 63) * CH + lane], g1 * __int_as_float(p1.y));
        }
        if (i < cnt) {
            int2 p = bin[i];
            float g = bf2f(cur[(size_t)(p.x & 0x1FFFF) * CH + lane]);
            atomicAdd(&accum[((p.x >> 17) & 63) * CH + lane], g * __int_as_float(p.y));
        }
        __syncthreads();
        for (int r = wid; r < RPB; r += 4) {
            int grow = ub * RPB + r;
            if (grow >= N_USERS) break;
            float x = accum[r * CH + lane];
            float ss = x * x;
            #pragma unroll
            for (int o = 32; o; o >>= 1) ss += __shfl_xor(ss, o, 64);
            float y = x / fmaxf(sqrtf(ss), 1e-12f);
            res_u[(size_t)grow * CH + lane] += y;
        }
    }
}

extern "C" void kernel_launch(void* const* d_in, const int* in_sizes, int n_in,
                              void* d_out, int out_size, void* d_ws, size_t ws_size,
                              hipStream_t stream) {
    const float* user_emb   = (const float*)d_in[0];
    const float* entity_emb = (const float*)d_in[1];
    const float* weight     = (const float*)d_in[2];
    const float* mask       = (const float*)d_in[3];
    const float* ivals      = (const float*)d_in[4];
    const int*   edge_head  = (const int*)d_in[5];
    const int*   edge_tail  = (const int*)d_in[6];
    const int*   edge_type  = (const int*)d_in[7];
    const int*   irows      = (const int*)d_in[8];
    const int*   icols      = (const int*)d_in[9];

    float* out_entity = (float*)d_out;
    float* out_user   = (float*)d_out + (size_t)N_ENTITIES * CH;

    // ---- workspace layout ----
    unsigned short* curA = (unsigned short*)d_ws;                 // 6.4M bf16 = 12.8 MB
    unsigned short* curB = curA + (size_t)N_ENTITIES * CH;        // 12.8 MB
    int2* binE = (int2*)(curB + (size_t)N_ENTITIES * CH);         // 1563*2560 int2 = 32 MB
    int2* binU = binE + (size_t)NB_E * CAP_E;                     // 782*3840 int2 = 24 MB
    int*  cntE = (int*)(binU + (size_t)NB_U * CAP_U);             // 1563
    int*  cntU = cntE + NB_E;                                     // 782

    // ---- build (bucket-binning only; identical for both hops) ----
    hipMemsetAsync(cntE, 0, (size_t)(NB_E + NB_U) * sizeof(int), stream);
    kg_pass1<<<P1_BLOCKS, 256, 0, stream>>>(edge_head, edge_tail, edge_type, mask,
                                            cntE, binE);
    usr_pass1<<<P1_BLOCKS, 256, 0, stream>>>(irows, icols, ivals, cntU, binU);

    // ---- init residuals (fp32) + bf16 current entity state ----
    {
        int n4 = N_ENTITIES * CH / 4;  // 1.6M
        init_kernel<<<(n4 + 255) / 256, 256, 0, stream>>>(
            (const float4*)user_emb, (const float4*)entity_emb,
            (ushort4*)curA, (float4*)out_entity, (float4*)out_user);
    }

    // ---- 2 hops, double-buffered bf16 entity state ----
    agg_kernel<<<NB_E + NB_U, 256, 0, stream>>>(
        curA, weight, binE, cntE, binU, cntU, curB, out_entity, out_user);
    agg_kernel<<<NB_E + NB_U, 256, 0, stream>>>(
        curB, weight, binE, cntE, binU, cntU, curA, out_entity, out_user);
}

// Round 5
// 4292.988 us; speedup vs baseline: 1.0402x; 1.0402x over previous
//
#include <hip/hip_runtime.h>

#define N_USERS 50000
#define N_ENTITIES 100000
#define N_RELATIONS 16
#define N_EDGES 3200000
#define NNZ 2500000
#define CH 64

#define RPB 64            // destination rows per bucket/block
#define NB_E 1563         // ceil(N_ENTITIES/64)
#define NB_U 782          // ceil(N_USERS/64)
#define CAP_E 2560        // bucket capacity (mean 2047, +11 sigma)
#define CAP_U 3840        // (mean 3197, +11 sigma)
#define P1_BLOCKS 512
#define CHUNK 1024        // staged entries per block-iteration

__device__ __forceinline__ unsigned short f2bf(float f) {
    unsigned u = __float_as_uint(f);
    u += 0x7FFF + ((u >> 16) & 1);   // round-to-nearest-even
    return (unsigned short)(u >> 16);
}
__device__ __forceinline__ float bf2f(unsigned short h) {
    return __uint_as_float(((unsigned)h) << 16);
}

// ---------------------------------------------------------------------------
// init: out_entity = entity_emb (f32); out_user = user_emb (f32);
//       curA = bf16(entity_emb)
// ---------------------------------------------------------------------------
__global__ void init_kernel(const float4* __restrict__ user_emb,
                            const float4* __restrict__ entity_emb,
                            ushort4* __restrict__ cur_bf,
                            float4* __restrict__ out_entity,
                            float4* __restrict__ out_user) {
    const int ne4 = N_ENTITIES * CH / 4;
    const int nu4 = N_USERS * CH / 4;
    int i = blockIdx.x * blockDim.x + threadIdx.x;
    if (i < ne4) {
        float4 v = entity_emb[i];
        out_entity[i] = v;
        ushort4 b;
        b.x = f2bf(v.x); b.y = f2bf(v.y); b.z = f2bf(v.z); b.w = f2bf(v.w);
        cur_bf[i] = b;
    }
    if (i < nu4) out_user[i] = user_emb[i];
}

// ---------------------------------------------------------------------------
// Bucket-binning pass (KG edges): per-block LDS histogram, one global atomic
// per (block,bucket) reserves a contiguous run. Payload:
// tail(17b) | rel(4b)<<17 | rowlocal(6b)<<21, mask fp32.
// ---------------------------------------------------------------------------
__global__ void kg_pass1(const int* __restrict__ head, const int* __restrict__ tail,
                         const int* __restrict__ type, const float* __restrict__ mask,
                         int* __restrict__ gcur, int2* __restrict__ bin) {
    __shared__ int hist[NB_E];
    __shared__ int lbase[NB_E];
    for (int i = threadIdx.x; i < NB_E; i += blockDim.x) hist[i] = 0;
    __syncthreads();
    const int chunk = (N_EDGES + P1_BLOCKS - 1) / P1_BLOCKS;
    int base = blockIdx.x * chunk;
    int lim = min(base + chunk, N_EDGES);
    for (int i = base + (int)threadIdx.x; i < lim; i += blockDim.x)
        atomicAdd(&hist[head[i] >> 6], 1);
    __syncthreads();
    for (int i = threadIdx.x; i < NB_E; i += blockDim.x) {
        int c = hist[i];
        lbase[i] = c ? atomicAdd(&gcur[i], c) : 0;
        hist[i] = 0;  // becomes local cursor
    }
    __syncthreads();
    for (int i = base + (int)threadIdx.x; i < lim; i += blockDim.x) {
        int h = head[i];
        int b = h >> 6;
        int loc = lbase[b] + atomicAdd(&hist[b], 1);
        if (loc < CAP_E)
            bin[(size_t)b * CAP_E + loc] =
                make_int2(tail[i] | ((type[i] - 1) << 17) | ((h & 63) << 21),
                          __float_as_int(mask[i]));
    }
}

// user interactions: payload = col(17b) | rowlocal(6b)<<17, val fp32
__global__ void usr_pass1(const int* __restrict__ rows, const int* __restrict__ cols,
                          const float* __restrict__ vals,
                          int* __restrict__ gcur, int2* __restrict__ bin) {
    __shared__ int hist[NB_U];
    __shared__ int lbase[NB_U];
    for (int i = threadIdx.x; i < NB_U; i += blockDim.x) hist[i] = 0;
    __syncthreads();
    const int chunk = (NNZ + P1_BLOCKS - 1) / P1_BLOCKS;
    int base = blockIdx.x * chunk;
    int lim = min(base + chunk, NNZ);
    for (int i = base + (int)threadIdx.x; i < lim; i += blockDim.x)
        atomicAdd(&hist[rows[i] >> 6], 1);
    __syncthreads();
    for (int i = threadIdx.x; i < NB_U; i += blockDim.x) {
        int c = hist[i];
        lbase[i] = c ? atomicAdd(&gcur[i], c) : 0;
        hist[i] = 0;
    }
    __syncthreads();
    for (int i = base + (int)threadIdx.x; i < lim; i += blockDim.x) {
        int r = rows[i];
        int b = r >> 6;
        int loc = lbase[b] + atomicAdd(&hist[b], 1);
        if (loc < CAP_U)
            bin[(size_t)b * CAP_U + loc] =
                make_int2(cols[i] | ((r & 63) << 17), __float_as_int(vals[i]));
    }
}

// ---------------------------------------------------------------------------
// Merged aggregation: one block per bucket; USER buckets first (longest jobs
// start earliest). Bucket entries are staged into LDS with coalesced
// block-wide loads (payload reads leave the latency chain); inner loop issues
// 4 independent bf16 gathers; accumulation via unsafeAtomicAdd -> ds_add_f32
// (no-return, no CAS loop, no lgkmcnt wait). Fused L2-norm + residual.
// ---------------------------------------------------------------------------
__global__ void __launch_bounds__(512)
agg_kernel(const unsigned short* __restrict__ cur,
           const float* __restrict__ weight,
           const int2* __restrict__ binE, const int* __restrict__ cntE,
           const int2* __restrict__ binU, const int* __restrict__ cntU,
           unsigned short* __restrict__ nxt,
           float* __restrict__ res_e, float* __restrict__ res_u) {
    __shared__ float accum[RPB * CH];          // 16 KB
    __shared__ float wlds[N_RELATIONS * CH];   // 4 KB
    __shared__ int2  stage[CHUNK];             // 8 KB
    const int b = blockIdx.x;
    const int t = threadIdx.x;
    const int wid = t >> 6;       // 0..7
    const int lane = t & 63;
    const bool is_user = (b < NB_U);
    const int eb = b - NB_U;
    const int2* __restrict__ bin = is_user ? (binU + (size_t)b * CAP_U)
                                           : (binE + (size_t)eb * CAP_E);
    const int cnt = is_user ? min(cntU[b], CAP_U) : min(cntE[eb], CAP_E);

    for (int i = t; i < RPB * CH; i += 512) accum[i] = 0.f;
    if (!is_user)
        for (int i = t; i < N_RELATIONS * CH; i += 512) wlds[i] = weight[i];
    __syncthreads();

    for (int base = 0; base < cnt; base += CHUNK) {
        const int m = min(CHUNK, cnt - base);
        for (int j = t; j < m; j += 512) stage[j] = bin[base + j];
        __syncthreads();
        const int s = wid * (CHUNK / 8);
        const int e = min(s + (CHUNK / 8), m);
        if (is_user) {
            int i = s;
            for (; i + 3 < e; i += 4) {
                int2 p0 = stage[i];
                int2 p1 = stage[i + 1];
                int2 p2 = stage[i + 2];
                int2 p3 = stage[i + 3];
                float g0 = bf2f(cur[(size_t)(p0.x & 0x1FFFF) * CH + lane]);
                float g1 = bf2f(cur[(size_t)(p1.x & 0x1FFFF) * CH + lane]);
                float g2 = bf2f(cur[(size_t)(p2.x & 0x1FFFF) * CH + lane]);
                float g3 = bf2f(cur[(size_t)(p3.x & 0x1FFFF) * CH + lane]);
                unsafeAtomicAdd(&accum[((p0.x >> 17) & 63) * CH + lane], g0 * __int_as_float(p0.y));
                unsafeAtomicAdd(&accum[((p1.x >> 17) & 63) * CH + lane], g1 * __int_as_float(p1.y));
                unsafeAtomicAdd(&accum[((p2.x >> 17) & 63) * CH + lane], g2 * __int_as_float(p2.y));
                unsafeAtomicAdd(&accum[((p3.x >> 17) & 63) * CH + lane], g3 * __int_as_float(p3.y));
            }
            for (; i < e; ++i) {
                int2 p = stage[i];
                float g = bf2f(cur[(size_t)(p.x & 0x1FFFF) * CH + lane]);
                unsafeAtomicAdd(&accum[((p.x >> 17) & 63) * CH + lane], g * __int_as_float(p.y));
            }
        } else {
            int i = s;
            for (; i + 3 < e; i += 4) {
                int2 p0 = stage[i];
                int2 p1 = stage[i + 1];
                int2 p2 = stage[i + 2];
                int2 p3 = stage[i + 3];
                float g0 = bf2f(cur[(size_t)(p0.x & 0x1FFFF) * CH + lane]);
                float g1 = bf2f(cur[(size_t)(p1.x & 0x1FFFF) * CH + lane]);
                float g2 = bf2f(cur[(size_t)(p2.x & 0x1FFFF) * CH + lane]);
                float g3 = bf2f(cur[(size_t)(p3.x & 0x1FFFF) * CH + lane]);
                float v0 = g0 * __int_as_float(p0.y) * wlds[((p0.x >> 17) & 15) * CH + lane];
                float v1 = g1 * __int_as_float(p1.y) * wlds[((p1.x >> 17) & 15) * CH + lane];
                float v2 = g2 * __int_as_float(p2.y) * wlds[((p2.x >> 17) & 15) * CH + lane];
                float v3 = g3 * __int_as_float(p3.y) * wlds[((p3.x >> 17) & 15) * CH + lane];
                unsafeAtomicAdd(&accum[((p0.x >> 21) & 63) * CH + lane], v0);
                unsafeAtomicAdd(&accum[((p1.x >> 21) & 63) * CH + lane], v1);
                unsafeAtomicAdd(&accum[((p2.x >> 21) & 63) * CH + lane], v2);
                unsafeAtomicAdd(&accum[((p3.x >> 21) & 63) * CH + lane], v3);
            }
            for (; i < e; ++i) {
                int2 p = stage[i];
                float g = bf2f(cur[(size_t)(p.x & 0x1FFFF) * CH + lane]);
                float v = g * __int_as_float(p.y) * wlds[((p.x >> 17) & 15) * CH + lane];
                unsafeAtomicAdd(&accum[((p.x >> 21) & 63) * CH + lane], v);
            }
        }
        __syncthreads();
    }

    if (is_user) {
        for (int r = wid; r < RPB; r += 8) {
            int grow = b * RPB + r;
            if (grow >= N_USERS) break;
            float x = accum[r * CH + lane];
            float ss = x * x;
            #pragma unroll
            for (int o = 32; o; o >>= 1) ss += __shfl_xor(ss, o, 64);
            float y = x / fmaxf(sqrtf(ss), 1e-12f);
            res_u[(size_t)grow * CH + lane] += y;
        }
    } else {
        for (int r = wid; r < RPB; r += 8) {
            int grow = eb * RPB + r;
            if (grow >= N_ENTITIES) break;
            float x = accum[r * CH + lane];
            float ss = x * x;
            #pragma unroll
            for (int o = 32; o; o >>= 1) ss += __shfl_xor(ss, o, 64);
            float y = x / fmaxf(sqrtf(ss), 1e-12f);
            nxt[(size_t)grow * CH + lane] = f2bf(y);
            res_e[(size_t)grow * CH + lane] += y;
        }
    }
}

extern "C" void kernel_launch(void* const* d_in, const int* in_sizes, int n_in,
                              void* d_out, int out_size, void* d_ws, size_t ws_size,
                              hipStream_t stream) {
    const float* user_emb   = (const float*)d_in[0];
    const float* entity_emb = (const float*)d_in[1];
    const float* weight     = (const float*)d_in[2];
    const float* mask       = (const float*)d_in[3];
    const float* ivals      = (const float*)d_in[4];
    const int*   edge_head  = (const int*)d_in[5];
    const int*   edge_tail  = (const int*)d_in[6];
    const int*   edge_type  = (const int*)d_in[7];
    const int*   irows      = (const int*)d_in[8];
    const int*   icols      = (const int*)d_in[9];

    float* out_entity = (float*)d_out;
    float* out_user   = (float*)d_out + (size_t)N_ENTITIES * CH;

    // ---- workspace layout ----
    unsigned short* curA = (unsigned short*)d_ws;                 // 12.8 MB
    unsigned short* curB = curA + (size_t)N_ENTITIES * CH;        // 12.8 MB
    int2* binE = (int2*)(curB + (size_t)N_ENTITIES * CH);         // 32 MB
    int2* binU = binE + (size_t)NB_E * CAP_E;                     // 24 MB
    int*  cntE = (int*)(binU + (size_t)NB_U * CAP_U);             // 1563
    int*  cntU = cntE + NB_E;                                     // 782

    // ---- build (bucket binning only; identical for both hops) ----
    hipMemsetAsync(cntE, 0, (size_t)(NB_E + NB_U) * sizeof(int), stream);
    kg_pass1<<<P1_BLOCKS, 256, 0, stream>>>(edge_head, edge_tail, edge_type, mask,
                                            cntE, binE);
    usr_pass1<<<P1_BLOCKS, 256, 0, stream>>>(irows, icols, ivals, cntU, binU);

    // ---- init residuals (fp32) + bf16 current entity state ----
    {
        int n4 = N_ENTITIES * CH / 4;
        init_kernel<<<(n4 + 255) / 256, 256, 0, stream>>>(
            (const float4*)user_emb, (const float4*)entity_emb,
            (ushort4*)curA, (float4*)out_entity, (float4*)out_user);
    }

    // ---- 2 hops, double-buffered bf16 entity state ----
    agg_kernel<<<NB_U + NB_E, 512, 0, stream>>>(
        curA, weight, binE, cntE, binU, cntU, curB, out_entity, out_user);
    agg_kernel<<<NB_U + NB_E, 512, 0, stream>>>(
        curB, weight, binE, cntE, binU, cntU, curA, out_entity, out_user);
}

// Round 6
// 772.223 us; speedup vs baseline: 5.7829x; 5.5593x over previous
//
#include <hip/hip_runtime.h>

#define N_USERS 50000
#define N_ENTITIES 100000
#define N_RELATIONS 16
#define N_EDGES 3200000
#define NNZ 2500000
#define CH 64

#define RPB 64            // destination rows per bucket/block
#define NB_E 1563         // ceil(N_ENTITIES/64)
#define NB_U 782          // ceil(N_USERS/64)
#define CAP_E 2560        // bucket capacity (mean 2047, +11 sigma)
#define CAP_U 3840        // (mean 3197, +11 sigma)
#define P1_BLOCKS 512
#define CHUNK 1024        // edges per block-iteration

__device__ __forceinline__ unsigned short f2bf(float f) {
    unsigned u = __float_as_uint(f);
    u += 0x7FFF + ((u >> 16) & 1);   // round-to-nearest-even
    return (unsigned short)(u >> 16);
}
__device__ __forceinline__ float bf2f(unsigned h) {
    return __uint_as_float(h << 16);
}

// ---------------------------------------------------------------------------
// init: out_entity = entity_emb (f32); out_user = user_emb (f32);
//       curA = bf16(entity_emb), packed as consecutive ushorts
// ---------------------------------------------------------------------------
__global__ void init_kernel(const float4* __restrict__ user_emb,
                            const float4* __restrict__ entity_emb,
                            ushort4* __restrict__ cur_bf,
                            float4* __restrict__ out_entity,
                            float4* __restrict__ out_user) {
    const int ne4 = N_ENTITIES * CH / 4;
    const int nu4 = N_USERS * CH / 4;
    int i = blockIdx.x * blockDim.x + threadIdx.x;
    if (i < ne4) {
        float4 v = entity_emb[i];
        out_entity[i] = v;
        ushort4 b;
        b.x = f2bf(v.x); b.y = f2bf(v.y); b.z = f2bf(v.z); b.w = f2bf(v.w);
        cur_bf[i] = b;
    }
    if (i < nu4) out_user[i] = user_emb[i];
}

// ---------------------------------------------------------------------------
// Bucket-binning pass (KG edges): per-block LDS histogram, one global atomic
// per (block,bucket) reserves a contiguous run. Payload:
// tail(17b) | rel(4b)<<17 | rowlocal(6b)<<21, mask fp32.
// ---------------------------------------------------------------------------
__global__ void kg_pass1(const int* __restrict__ head, const int* __restrict__ tail,
                         const int* __restrict__ type, const float* __restrict__ mask,
                         int* __restrict__ gcur, int2* __restrict__ bin) {
    __shared__ int hist[NB_E];
    __shared__ int lbase[NB_E];
    for (int i = threadIdx.x; i < NB_E; i += blockDim.x) hist[i] = 0;
    __syncthreads();
    const int chunk = (N_EDGES + P1_BLOCKS - 1) / P1_BLOCKS;
    int base = blockIdx.x * chunk;
    int lim = min(base + chunk, N_EDGES);
    for (int i = base + (int)threadIdx.x; i < lim; i += blockDim.x)
        atomicAdd(&hist[head[i] >> 6], 1);
    __syncthreads();
    for (int i = threadIdx.x; i < NB_E; i += blockDim.x) {
        int c = hist[i];
        lbase[i] = c ? atomicAdd(&gcur[i], c) : 0;
        hist[i] = 0;  // becomes local cursor
    }
    __syncthreads();
    for (int i = base + (int)threadIdx.x; i < lim; i += blockDim.x) {
        int h = head[i];
        int b = h >> 6;
        int loc = lbase[b] + atomicAdd(&hist[b], 1);
        if (loc < CAP_E)
            bin[(size_t)b * CAP_E + loc] =
                make_int2(tail[i] | ((type[i] - 1) << 17) | ((h & 63) << 21),
                          __float_as_int(mask[i]));
    }
}

// user interactions: payload = col(17b) | rowlocal(6b)<<17, val fp32
__global__ void usr_pass1(const int* __restrict__ rows, const int* __restrict__ cols,
                          const float* __restrict__ vals,
                          int* __restrict__ gcur, int2* __restrict__ bin) {
    __shared__ int hist[NB_U];
    __shared__ int lbase[NB_U];
    for (int i = threadIdx.x; i < NB_U; i += blockDim.x) hist[i] = 0;
    __syncthreads();
    const int chunk = (NNZ + P1_BLOCKS - 1) / P1_BLOCKS;
    int base = blockIdx.x * chunk;
    int lim = min(base + chunk, NNZ);
    for (int i = base + (int)threadIdx.x; i < lim; i += blockDim.x)
        atomicAdd(&hist[rows[i] >> 6], 1);
    __syncthreads();
    for (int i = threadIdx.x; i < NB_U; i += blockDim.x) {
        int c = hist[i];
        lbase[i] = c ? atomicAdd(&gcur[i], c) : 0;
        hist[i] = 0;
    }
    __syncthreads();
    for (int i = base + (int)threadIdx.x; i < lim; i += blockDim.x) {
        int r = rows[i];
        int b = r >> 6;
        int loc = lbase[b] + atomicAdd(&hist[b], 1);
        if (loc < CAP_U)
            bin[(size_t)b * CAP_U + loc] =
                make_int2(cols[i] | ((r & 63) << 17), __float_as_int(vals[i]));
    }
}

// ---------------------------------------------------------------------------
// Aggregation v3: one block (512 thr = 8 waves) per 64-row bucket; user
// buckets first. Per 1024-edge chunk: coalesced loads into registers ->
// LDS counting sort by rowlocal (int ds_add_rtn ranks + 64-lane scan) ->
// row-sorted LDS buffer -> wave w accumulates rows 8w..8w+7 in REGISTERS
// (no fp atomics). Gathers are dword loads of packed bf16 pairs (2 lanes
// share a dword, each extracts a half). Fused L2-norm + residual epilogue.
// ---------------------------------------------------------------------------
__global__ void __launch_bounds__(512)
agg_kernel(const unsigned int* __restrict__ cur32,   // bf16 pairs, 32 dwords/row
           const float* __restrict__ weight,
           const int2* __restrict__ binE, const int* __restrict__ cntE,
           const int2* __restrict__ binU, const int* __restrict__ cntU,
           unsigned short* __restrict__ nxt,
           float* __restrict__ res_e, float* __restrict__ res_u) {
    __shared__ int2  sorted[CHUNK];            // 8 KB
    __shared__ int   hist[RPB];                // 256 B
    __shared__ int   offs[RPB + 1];            // 260 B
    __shared__ float wlds[N_RELATIONS * CH];   // 4 KB

    const int b = blockIdx.x;
    const int t = threadIdx.x;
    const int w = t >> 6;        // wave 0..7
    const int lane = t & 63;
    const bool is_user = (b < NB_U);
    const int eb = b - NB_U;
    const int2* __restrict__ bin = is_user ? (binU + (size_t)b * CAP_U)
                                           : (binE + (size_t)eb * CAP_E);
    const int cnt = is_user ? min(cntU[b], CAP_U) : min(cntE[eb], CAP_E);
    const int rsh = is_user ? 17 : 21;    // rowlocal bit position

    if (!is_user)
        for (int i = t; i < N_RELATIONS * CH; i += 512) wlds[i] = weight[i];

    float acc[8];
    #pragma unroll
    for (int rr = 0; rr < 8; ++rr) acc[rr] = 0.f;

    const int half = lane >> 1;          // dword index within row
    const int hi = lane & 1;             // which half of the dword

    for (int base = 0; base < cnt; base += CHUNK) {
        const int m = min(CHUNK, cnt - base);
        // issue coalesced payload loads (registers) before touching LDS
        int2 e0, e1;
        int r0 = -1, r1 = -1, k0 = 0, k1 = 0;
        const int j0 = t, j1 = t + 512;
        if (j0 < m) e0 = bin[base + j0];
        if (j1 < m) e1 = bin[base + j1];
        if (t < RPB) hist[t] = 0;
        __syncthreads();   // hist cleared; prev chunk fully processed
        if (j0 < m) { r0 = (e0.x >> rsh) & 63; k0 = atomicAdd(&hist[r0], 1); }
        if (j1 < m) { r1 = (e1.x >> rsh) & 63; k1 = atomicAdd(&hist[r1], 1); }
        __syncthreads();   // counts final
        if (t < 64) {      // wave 0: exclusive scan of 64 counts
            int v = hist[t];
            int s = v;
            #pragma unroll
            for (int d = 1; d < 64; d <<= 1) {
                int nb = __shfl_up(s, d, 64);
                if (t >= d) s += nb;
            }
            offs[t] = s - v;
            if (t == 63) offs[64] = s;
        }
        __syncthreads();   // offs ready
        if (j0 < m) sorted[offs[r0] + k0] = e0;
        if (j1 < m) sorted[offs[r1] + k1] = e1;
        __syncthreads();   // sorted ready

        if (is_user) {
            #pragma unroll
            for (int rr = 0; rr < 8; ++rr) {
                const int row = (w << 3) + rr;
                int s = offs[row], e = offs[row + 1];
                float a = acc[rr];
                int i = s;
                for (; i + 1 < e; i += 2) {
                    int2 p0 = sorted[i];
                    int2 p1 = sorted[i + 1];
                    unsigned w0 = cur32[(size_t)(p0.x & 0x1FFFF) * 32 + half];
                    unsigned w1 = cur32[(size_t)(p1.x & 0x1FFFF) * 32 + half];
                    float g0 = bf2f(hi ? (w0 >> 16) : (w0 & 0xFFFF));
                    float g1 = bf2f(hi ? (w1 >> 16) : (w1 & 0xFFFF));
                    a += g0 * __int_as_float(p0.y);
                    a += g1 * __int_as_float(p1.y);
                }
                if (i < e) {
                    int2 p = sorted[i];
                    unsigned w0 = cur32[(size_t)(p.x & 0x1FFFF) * 32 + half];
                    a += bf2f(hi ? (w0 >> 16) : (w0 & 0xFFFF)) * __int_as_float(p.y);
                }
                acc[rr] = a;
            }
        } else {
            #pragma unroll
            for (int rr = 0; rr < 8; ++rr) {
                const int row = (w << 3) + rr;
                int s = offs[row], e = offs[row + 1];
                float a = acc[rr];
                int i = s;
                for (; i + 1 < e; i += 2) {
                    int2 p0 = sorted[i];
                    int2 p1 = sorted[i + 1];
                    unsigned w0 = cur32[(size_t)(p0.x & 0x1FFFF) * 32 + half];
                    unsigned w1 = cur32[(size_t)(p1.x & 0x1FFFF) * 32 + half];
                    float g0 = bf2f(hi ? (w0 >> 16) : (w0 & 0xFFFF));
                    float g1 = bf2f(hi ? (w1 >> 16) : (w1 & 0xFFFF));
                    a += g0 * __int_as_float(p0.y) * wlds[((p0.x >> 17) & 15) * CH + lane];
                    a += g1 * __int_as_float(p1.y) * wlds[((p1.x >> 17) & 15) * CH + lane];
                }
                if (i < e) {
                    int2 p = sorted[i];
                    unsigned w0 = cur32[(size_t)(p.x & 0x1FFFF) * 32 + half];
                    a += bf2f(hi ? (w0 >> 16) : (w0 & 0xFFFF)) * __int_as_float(p.y)
                       * wlds[((p.x >> 17) & 15) * CH + lane];
                }
                acc[rr] = a;
            }
        }
        __syncthreads();   // done reading sorted/offs before next chunk rewrites
    }

    // epilogue: fused L2-normalize + residual (+ next-state for entities)
    #pragma unroll
    for (int rr = 0; rr < 8; ++rr) {
        const int row = (w << 3) + rr;
        float x = acc[rr];
        float ss = x * x;
        #pragma unroll
        for (int o = 32; o; o >>= 1) ss += __shfl_xor(ss, o, 64);
        float y = x / fmaxf(sqrtf(ss), 1e-12f);
        if (is_user) {
            int grow = b * RPB + row;
            if (grow < N_USERS) res_u[(size_t)grow * CH + lane] += y;
        } else {
            int grow = eb * RPB + row;
            if (grow < N_ENTITIES) {
                nxt[(size_t)grow * CH + lane] = f2bf(y);
                res_e[(size_t)grow * CH + lane] += y;
            }
        }
    }
}

extern "C" void kernel_launch(void* const* d_in, const int* in_sizes, int n_in,
                              void* d_out, int out_size, void* d_ws, size_t ws_size,
                              hipStream_t stream) {
    const float* user_emb   = (const float*)d_in[0];
    const float* entity_emb = (const float*)d_in[1];
    const float* weight     = (const float*)d_in[2];
    const float* mask       = (const float*)d_in[3];
    const float* ivals      = (const float*)d_in[4];
    const int*   edge_head  = (const int*)d_in[5];
    const int*   edge_tail  = (const int*)d_in[6];
    const int*   edge_type  = (const int*)d_in[7];
    const int*   irows      = (const int*)d_in[8];
    const int*   icols      = (const int*)d_in[9];

    float* out_entity = (float*)d_out;
    float* out_user   = (float*)d_out + (size_t)N_ENTITIES * CH;

    // ---- workspace layout ----
    unsigned short* curA = (unsigned short*)d_ws;                 // 12.8 MB
    unsigned short* curB = curA + (size_t)N_ENTITIES * CH;        // 12.8 MB
    int2* binE = (int2*)(curB + (size_t)N_ENTITIES * CH);         // 32 MB
    int2* binU = binE + (size_t)NB_E * CAP_E;                     // 24 MB
    int*  cntE = (int*)(binU + (size_t)NB_U * CAP_U);             // 1563
    int*  cntU = cntE + NB_E;                                     // 782

    // ---- build (bucket binning only; identical for both hops) ----
    hipMemsetAsync(cntE, 0, (size_t)(NB_E + NB_U) * sizeof(int), stream);
    kg_pass1<<<P1_BLOCKS, 256, 0, stream>>>(edge_head, edge_tail, edge_type, mask,
                                            cntE, binE);
    usr_pass1<<<P1_BLOCKS, 256, 0, stream>>>(irows, icols, ivals, cntU, binU);

    // ---- init residuals (fp32) + bf16 current entity state ----
    {
        int n4 = N_ENTITIES * CH / 4;
        init_kernel<<<(n4 + 255) / 256, 256, 0, stream>>>(
            (const float4*)user_emb, (const float4*)entity_emb,
            (ushort4*)curA, (float4*)out_entity, (float4*)out_user);
    }

    // ---- 2 hops, double-buffered bf16 entity state ----
    agg_kernel<<<NB_U + NB_E, 512, 0, stream>>>(
        (const unsigned int*)curA, weight, binE, cntE, binU, cntU,
        curB, out_entity, out_user);
    agg_kernel<<<NB_U + NB_E, 512, 0, stream>>>(
        (const unsigned int*)curB, weight, binE, cntE, binU, cntU,
        curA, out_entity, out_user);
}